// Round 5
// baseline (425.100 us; speedup 1.0000x reference)
//
#include <hip/hip_runtime.h>

#define T_SEQ 2048
#define U_DIM 1024
#define H_HEADS 16
#define D_HEAD 64
#define B_BATCH 4
#define KVBLK 64
#define QBLK 128
#define NITER (T_SEQ / KVBLK)

typedef float f32x16 __attribute__((ext_vector_type(16)));
typedef float f32x4  __attribute__((ext_vector_type(4)));
typedef __bf16 bf16x8 __attribute__((ext_vector_type(8)));
typedef unsigned int uint4v __attribute__((ext_vector_type(4)));
typedef unsigned int uint2v __attribute__((ext_vector_type(2)));
typedef unsigned short u16;

#if __has_builtin(__builtin_amdgcn_exp2f)
#define EXP2(x) __builtin_amdgcn_exp2f(x)
#else
#define EXP2(x) exp2f(x)
#endif

__device__ __forceinline__ unsigned f2bf_pack(float lo, float hi) {
    __bf16 a = (__bf16)lo, b = (__bf16)hi;
    unsigned short ua = __builtin_bit_cast(unsigned short, a);
    unsigned short ub = __builtin_bit_cast(unsigned short, b);
    return (unsigned)ua | ((unsigned)ub << 16);
}

__device__ __forceinline__ void gl2lds16(const void* g, void* l) {
    __builtin_amdgcn_global_load_lds(
        (const __attribute__((address_space(1))) void*)g,
        (__attribute__((address_space(3))) void*)l, 16, 0, 0);
}

// ---------------- pre-pass A: K fp32 [b,t,h*64+d] -> bf16 [b,h,t,d] ----------------
__global__ __launch_bounds__(256) void conv_k(const float* __restrict__ K, u16* __restrict__ Kb) {
    unsigned idx = blockIdx.x * 256u + threadIdx.x;   // 2^20 threads
    unsigned d8 = idx & 7, t = (idx >> 3) & 2047, h = (idx >> 14) & 15, b = idx >> 18;
    const float* src = K + (((size_t)(b * 2048 + t)) * 1024 + h * 64 + d8 * 8);
    f32x4 a = *(const f32x4*)src;
    f32x4 c = *(const f32x4*)(src + 4);
    uint4v u = { f2bf_pack(a.x, a.y), f2bf_pack(a.z, a.w),
                 f2bf_pack(c.x, c.y), f2bf_pack(c.z, c.w) };
    *(uint4v*)(Kb + (((size_t)(b * 16 + h) * 2048 + t) * 64 + d8 * 8)) = u;
}

// ---------------- pre-pass B: V fp32 [b,t,h*64+d] -> bf16 transposed [b,h,d,t] ----------------
__global__ __launch_bounds__(256) void transp_v(const float* __restrict__ V, u16* __restrict__ Vt) {
    __shared__ __align__(16) u16 tile[64][72];
    const int tid = threadIdx.x;
    const int bid = blockIdx.x;                  // 2048 = 4b * 16h * 32 t-tiles
    const int tt = bid & 31, h = (bid >> 5) & 15, b = bid >> 9;
    const int t0 = tt * 64;
    {
        const int r = tid >> 2, q = tid & 3;
        const float* src = V + (((size_t)(b * 2048 + t0 + r)) * 1024 + h * 64 + q * 16);
        f32x4 v0 = *(const f32x4*)(src);
        f32x4 v1 = *(const f32x4*)(src + 4);
        f32x4 v2 = *(const f32x4*)(src + 8);
        f32x4 v3 = *(const f32x4*)(src + 12);
#pragma unroll
        for (int j = 0; j < 4; ++j) {
            tile[q * 16 + 0  + j][r] = __builtin_bit_cast(u16, (__bf16)v0[j]);
            tile[q * 16 + 4  + j][r] = __builtin_bit_cast(u16, (__bf16)v1[j]);
            tile[q * 16 + 8  + j][r] = __builtin_bit_cast(u16, (__bf16)v2[j]);
            tile[q * 16 + 12 + j][r] = __builtin_bit_cast(u16, (__bf16)v3[j]);
        }
    }
    __syncthreads();
    {
        const int d = tid >> 2, q = tid & 3;
        u16* dst = Vt + (((size_t)(b * 16 + h) * 64 + d) * 2048 + t0 + q * 16);
        *(uint4v*)(dst)     = *(const uint4v*)&tile[d][q * 16];
        *(uint4v*)(dst + 8) = *(const uint4v*)&tile[d][q * 16 + 8];
    }
}

// ------- main kernel v5: 1.5-deep cross-tile phase pipeline (QK(t) MFMA ∥ softmax+PV(prev)) -------
__global__ __launch_bounds__(256, 4) void mha_fwd5(
    const float* __restrict__ Q, const u16* __restrict__ Kb,
    const u16* __restrict__ Vt, float* __restrict__ O)
{
    const int tid  = threadIdx.x;
    const int wave = tid >> 6;
    const int lane = tid & 63;
    const int li   = lane & 31;
    const int hi   = lane >> 5;
    const int sw   = (li & 7) << 4;    // read-side XOR swizzle

    // XCD colocation: bid%8 == bh%8 -> all 16 q-tiles of one (b,h) share an XCD's L2
    const int bid = blockIdx.x;        // 1024
    const int bh  = bid & 63;
    const int qt  = bid >> 6;
    const int b   = bh >> 4;

    __shared__ __align__(16) u16 sK[2][4096];   // [buf][key(64) x d(64)] swizzled
    __shared__ __align__(16) u16 sVt[2][4096];  // [buf][d(64) x key(64)] swizzled

    const int c0 = wave * 2;
    const int r0 = lane >> 3;
    const int innerK = ((lane & 7) * 16) ^ (r0 << 4);
    const char* kbg = (const char*)Kb + (size_t)bh * 262144;
    const char* vbg = (const char*)Vt + (size_t)bh * 262144;
    const char* kp0 = kbg + c0 * 1024 + r0 * 128 + innerK;
    const char* kp1 = kbg + (c0 + 1) * 1024 + r0 * 128 + innerK;
    const char* vp0 = vbg + (size_t)(c0 * 8 + r0) * 4096 + innerK;
    const char* vp1 = vbg + (size_t)((c0 + 1) * 8 + r0) * 4096 + innerK;

#define STAGE_K(BUF) do {                                                 \
        char* kd = (char*)&sK[(BUF)][0] + c0 * 1024;                      \
        gl2lds16(kp0, kd); gl2lds16(kp1, kd + 1024);                      \
        kp0 += 8192; kp1 += 8192; } while (0)
#define STAGE_V(BUF) do {                                                 \
        char* vd = (char*)&sVt[(BUF)][0] + c0 * 1024;                     \
        gl2lds16(vp0, vd); gl2lds16(vp1, vd + 1024);                      \
        vp0 += 128; vp1 += 128; } while (0)

#define WAIT_BAR do { asm volatile("s_waitcnt vmcnt(0)" ::: "memory");    \
        __builtin_amdgcn_s_barrier();                                     \
        asm volatile("" ::: "memory"); } while (0)
#define BAR_ONLY do { asm volatile("" ::: "memory");                      \
        __builtin_amdgcn_s_barrier();                                     \
        asm volatile("" ::: "memory"); } while (0)

    // pack 8 probs (rows RB..RB+7 of SF) -> bf16 P-frag, 2 PV MFMAs from V buf
#define PACKPV(SF, RB, KS, VBUF)                                                \
    {                                                                           \
        unsigned x1 = f2bf_pack(SF[(RB) + 0], SF[(RB) + 1]);                    \
        unsigned x2 = f2bf_pack(SF[(RB) + 2], SF[(RB) + 3]);                    \
        unsigned y1 = f2bf_pack(SF[(RB) + 4], SF[(RB) + 5]);                    \
        unsigned y2 = f2bf_pack(SF[(RB) + 6], SF[(RB) + 7]);                    \
        auto r1 = __builtin_amdgcn_permlane32_swap(x1, y1, false, false);       \
        auto r2 = __builtin_amdgcn_permlane32_swap(x2, y2, false, false);       \
        uint4v pw = { (unsigned)r1[0], (unsigned)r2[0],                         \
                      (unsigned)r1[1], (unsigned)r2[1] };                       \
        bf16x8 pf = __builtin_bit_cast(bf16x8, pw);                             \
        bf16x8 vta = *(const bf16x8*)((const char*)&sVt[VBUF][0] + li * 128 +   \
                                      ((32 * (KS) + 16 * hi) ^ sw));            \
        bf16x8 vtb = *(const bf16x8*)((const char*)&sVt[VBUF][0] + (32 + li) * 128 + \
                                      ((32 * (KS) + 16 * hi) ^ sw));            \
        accO0 = __builtin_amdgcn_mfma_f32_32x32x16_bf16(vta, pf, accO0, 0, 0, 0); \
        accO1 = __builtin_amdgcn_mfma_f32_32x32x16_bf16(vtb, pf, accO1, 0, 0, 0); \
    }

    // one phase: build SQK (4 QK MFMAs, rows ROWOFF..ROWOFF+31 of K tile in sK[KBUF])
    // interleaved with the softmax-finish of SFIN (16 exp2 + lacc + 2 PACKPV groups)
#define PHASE(SQK, KBUF, ROWOFF, SFIN, VBUF, KSBASE)                            \
    {                                                                           \
        const char* krow_ = (const char*)&sK[KBUF][0] + ((ROWOFF) + li) * 128;  \
        bf16x8 kf0 = *(const bf16x8*)(krow_ + ((16 * hi) ^ sw));                \
        bf16x8 kf1 = *(const bf16x8*)(krow_ + ((32 + 16 * hi) ^ sw));           \
        SQK = (f32x16){};                                                       \
        _Pragma("unroll") for (int r = 0; r < 8; ++r) SFIN[r] = EXP2(SFIN[r]);  \
        SQK = __builtin_amdgcn_mfma_f32_32x32x16_bf16(kf0, qfrag[0], SQK, 0, 0, 0); \
        _Pragma("unroll") for (int r = 8; r < 16; ++r) SFIN[r] = EXP2(SFIN[r]); \
        SQK = __builtin_amdgcn_mfma_f32_32x32x16_bf16(kf1, qfrag[1], SQK, 0, 0, 0); \
        bf16x8 kf2 = *(const bf16x8*)(krow_ + ((64 + 16 * hi) ^ sw));           \
        bf16x8 kf3 = *(const bf16x8*)(krow_ + ((96 + 16 * hi) ^ sw));           \
        lacc[0] += (SFIN[0] + SFIN[1]) + (SFIN[2] + SFIN[3]);                   \
        lacc[1] += (SFIN[4] + SFIN[5]) + (SFIN[6] + SFIN[7]);                   \
        PACKPV(SFIN, 0, (KSBASE), VBUF)                                         \
        SQK = __builtin_amdgcn_mfma_f32_32x32x16_bf16(kf2, qfrag[2], SQK, 0, 0, 0); \
        lacc[2] += (SFIN[8] + SFIN[9]) + (SFIN[10] + SFIN[11]);                 \
        lacc[3] += (SFIN[12] + SFIN[13]) + (SFIN[14] + SFIN[15]);               \
        PACKPV(SFIN, 8, (KSBASE) + 1, VBUF)                                     \
        SQK = __builtin_amdgcn_mfma_f32_32x32x16_bf16(kf3, qfrag[3], SQK, 0, 0, 0); \
    }

#define QK_BARE(SQK, KBUF, ROWOFF)                                              \
    {                                                                           \
        const char* krow_ = (const char*)&sK[KBUF][0] + ((ROWOFF) + li) * 128;  \
        SQK = (f32x16){};                                                       \
        _Pragma("unroll") for (int ds = 0; ds < 4; ++ds) {                      \
            bf16x8 kf = *(const bf16x8*)(krow_ + ((32 * ds + 16 * hi) ^ sw));   \
            SQK = __builtin_amdgcn_mfma_f32_32x32x16_bf16(kf, qfrag[ds], SQK, 0, 0, 0); \
        }                                                                       \
    }

#define FIN_ONLY(SFIN, VBUF, KSBASE)                                            \
    {                                                                           \
        _Pragma("unroll") for (int r = 0; r < 16; ++r) SFIN[r] = EXP2(SFIN[r]); \
        lacc[0] += (SFIN[0] + SFIN[1]) + (SFIN[2] + SFIN[3]);                   \
        lacc[1] += (SFIN[4] + SFIN[5]) + (SFIN[6] + SFIN[7]);                   \
        lacc[2] += (SFIN[8] + SFIN[9]) + (SFIN[10] + SFIN[11]);                 \
        lacc[3] += (SFIN[12] + SFIN[13]) + (SFIN[14] + SFIN[15]);               \
        PACKPV(SFIN, 0, (KSBASE), VBUF)                                         \
        PACKPV(SFIN, 8, (KSBASE) + 1, VBUF)                                     \
    }

    STAGE_K(0); STAGE_V(0);    // tile 0 -> buf0

    // ---- Q fragments with (1/8)*log2(e) folded in ----
    const float cexp = 0.18033688011112042f;
    const int qrow = qt * QBLK + wave * 32 + li;
    const float* qp = Q + ((size_t)(b * T_SEQ + qrow) * U_DIM + (bh & 15) * D_HEAD);
    bf16x8 qfrag[4];
#pragma unroll
    for (int ds = 0; ds < 4; ++ds) {
        f32x4 a = *(const f32x4*)(qp + 16 * ds + 8 * hi);
        f32x4 c = *(const f32x4*)(qp + 16 * ds + 8 * hi + 4);
        uint4v u = { f2bf_pack(a.x * cexp, a.y * cexp), f2bf_pack(a.z * cexp, a.w * cexp),
                     f2bf_pack(c.x * cexp, c.y * cexp), f2bf_pack(c.z * cexp, c.w * cexp) };
        qfrag[ds] = __builtin_bit_cast(bf16x8, u);
    }

    f32x4 lacc = {};
    f32x16 accO0 = {}, accO1 = {};
    f32x16 s0, s1;

    // ---- prologue: tile 0 ----
    WAIT_BAR;                   // tile 0 landed in buf0
    STAGE_K(1);                 // tile 1 K -> buf1
    __builtin_amdgcn_s_setprio(1);
    QK_BARE(s0, 0, 0);          // tile0 half0 (nothing to overlap, once)
    __builtin_amdgcn_s_setprio(0);
    BAR_ONLY;
    STAGE_V(1);                 // tile 1 V -> buf1
    __builtin_amdgcn_s_setprio(1);
    PHASE(s1, 0, 32, s0, 0, 0); // QK1(tile0) || finish s0(tile0) w/ buf0 V
    __builtin_amdgcn_s_setprio(0);

    // ---- pipelined pairs: tiles (1,2),(3,4),...,(29,30) ----
#pragma unroll 1
    for (int t = 1; t < NITER - 1; t += 2) {
        // iter t (odd tile -> buf1; prev tile t-1 even -> buf0)
        WAIT_BAR;                    // tile t landed in buf1
        STAGE_K(0);                  // tile t+1 K -> buf0 (old K dead)
        __builtin_amdgcn_s_setprio(1);
        PHASE(s0, 1, 0, s1, 0, 2);   // QK0(t) || finish s1(t-1) w/ buf0 V
        __builtin_amdgcn_s_setprio(0);
        BAR_ONLY;                    // all waves done reading buf0 V
        STAGE_V(0);                  // tile t+1 V -> buf0
        __builtin_amdgcn_s_setprio(1);
        PHASE(s1, 1, 32, s0, 1, 0);  // QK1(t) || finish s0(t) w/ buf1 V
        __builtin_amdgcn_s_setprio(0);

        // iter t+1 (even tile -> buf0; prev tile t odd -> buf1)
        WAIT_BAR;                    // tile t+1 landed in buf0
        STAGE_K(1);                  // tile t+2 K -> buf1
        __builtin_amdgcn_s_setprio(1);
        PHASE(s0, 0, 0, s1, 1, 2);   // QK0(t+1) || finish s1(t) w/ buf1 V
        __builtin_amdgcn_s_setprio(0);
        BAR_ONLY;
        STAGE_V(1);                  // tile t+2 V -> buf1
        __builtin_amdgcn_s_setprio(1);
        PHASE(s1, 0, 32, s0, 0, 0);  // QK1(t+1) || finish s0(t+1) w/ buf0 V
        __builtin_amdgcn_s_setprio(0);
    }

    // ---- peeled tile 31 (buf1; tile 30 in buf0) ----
    WAIT_BAR;                        // tile 31 landed in buf1
    __builtin_amdgcn_s_setprio(1);
    PHASE(s0, 1, 0, s1, 0, 2);       // QK0(31) || finish s1(30) w/ buf0 V
    PHASE(s1, 1, 32, s0, 1, 0);      // QK1(31) || finish s0(31) w/ buf1 V
    FIN_ONLY(s1, 1, 2);              // finish s1(31) w/ buf1 V
    __builtin_amdgcn_s_setprio(0);

#undef STAGE_K
#undef STAGE_V
#undef WAIT_BAR
#undef BAR_ONLY
#undef PACKPV
#undef PHASE
#undef QK_BARE
#undef FIN_ONLY

    // ---- epilogue ----
    float lsum = (lacc[0] + lacc[1]) + (lacc[2] + lacc[3]);
    float lt = lsum + __shfl_xor(lsum, 32);
    const float invl = 1.0f / lt;
    float* op = O + ((size_t)(b * T_SEQ + qrow) * U_DIM + (bh & 15) * D_HEAD);
#pragma unroll
    for (int rq = 0; rq < 4; ++rq) {
        f32x4 o0 = { accO0[4 * rq + 0] * invl, accO0[4 * rq + 1] * invl,
                     accO0[4 * rq + 2] * invl, accO0[4 * rq + 3] * invl };
        *(f32x4*)(op + 8 * rq + 4 * hi) = o0;
        f32x4 o1 = { accO1[4 * rq + 0] * invl, accO1[4 * rq + 1] * invl,
                     accO1[4 * rq + 2] * invl, accO1[4 * rq + 3] * invl };
        *(f32x4*)(op + 8 * rq + 4 * hi + 32) = o1;
    }
}

// ---------------- fallback (round-1 kernel, known good) for small ws ----------------
__global__ __launch_bounds__(256, 2) void mha_fwd_v1(
    const float* __restrict__ Q, const float* __restrict__ K,
    const float* __restrict__ V, float* __restrict__ O)
{
    const int tid  = threadIdx.x;
    const int wave = tid >> 6;
    const int lane = tid & 63;
    const int li   = lane & 31;
    const int hi   = lane >> 5;
    const int bid = blockIdx.x;
    const int qt  = bid & 15;
    const int bh  = bid >> 4;
    const int b   = bh >> 4;
    const int hd  = bh & 15;
    __shared__ __align__(16) u16 sK[KVBLK * D_HEAD];
    __shared__ __align__(16) u16 sV[KVBLK * D_HEAD];
    const int qrow = qt * QBLK + wave * 32 + li;
    const float* qp = Q + ((size_t)(b * T_SEQ + qrow) * U_DIM + hd * D_HEAD);
    bf16x8 qfrag[4];
#pragma unroll
    for (int ds = 0; ds < 4; ++ds) {
        f32x4 a = *(const f32x4*)(qp + 16 * ds + 8 * hi);
        f32x4 c = *(const f32x4*)(qp + 16 * ds + 8 * hi + 4);
        uint4v u = { f2bf_pack(a.x, a.y), f2bf_pack(a.z, a.w),
                     f2bf_pack(c.x, c.y), f2bf_pack(c.z, c.w) };
        qfrag[ds] = __builtin_bit_cast(bf16x8, u);
    }
    const int d4 = tid & 15;
    const int kq = tid >> 4;
    const float* kbase = K + ((size_t)(b * T_SEQ) * U_DIM + hd * D_HEAD);
    const float* vbase = V + ((size_t)(b * T_SEQ) * U_DIM + hd * D_HEAD);
    const float cexp = 0.18033688011112042f;
    float m = -INFINITY, lsum = 0.0f;
    f32x16 accO0 = {}, accO1 = {};
    for (int it = 0; it < NITER; ++it) {
        const int kv0 = it * KVBLK;
        {
            const float* kr = kbase + (size_t)(kv0 + 4 * kq) * U_DIM + 4 * d4;
            const float* vr = vbase + (size_t)(kv0 + 4 * kq) * U_DIM + 4 * d4;
            f32x4 kv[4], vv[4];
#pragma unroll
            for (int i = 0; i < 4; ++i) {
                kv[i] = *(const f32x4*)(kr + i * U_DIM);
                vv[i] = *(const f32x4*)(vr + i * U_DIM);
            }
#pragma unroll
            for (int i = 0; i < 4; ++i) {
                int row = 4 * kq + i;
                char* dst = (char*)sK + row * 128 + ((8 * d4) ^ ((row & 7) << 4));
                uint2v w = { f2bf_pack(kv[i].x, kv[i].y), f2bf_pack(kv[i].z, kv[i].w) };
                *(uint2v*)dst = w;
            }
#pragma unroll
            for (int jj = 0; jj < 4; ++jj) {
                int row = 4 * d4 + jj;
                char* dst = (char*)sV + row * 128 + ((8 * kq) ^ ((row & 7) << 4));
                uint2v w = { f2bf_pack(vv[0][jj], vv[1][jj]),
                             f2bf_pack(vv[2][jj], vv[3][jj]) };
                *(uint2v*)dst = w;
            }
        }
        __syncthreads();
        f32x16 s0 = {}, s1 = {};
#pragma unroll
        for (int ds = 0; ds < 4; ++ds) {
            bf16x8 kf0 = *(const bf16x8*)((const char*)sK + li * 128 +
                                          ((32 * ds + 16 * hi) ^ ((li & 7) << 4)));
            bf16x8 kf1 = *(const bf16x8*)((const char*)sK + (32 + li) * 128 +
                                          ((32 * ds + 16 * hi) ^ ((li & 7) << 4)));
            s0 = __builtin_amdgcn_mfma_f32_32x32x16_bf16(kf0, qfrag[ds], s0, 0, 0, 0);
            s1 = __builtin_amdgcn_mfma_f32_32x32x16_bf16(kf1, qfrag[ds], s1, 0, 0, 0);
        }
        float tm = s0[0];
#pragma unroll
        for (int r = 1; r < 16; ++r) tm = fmaxf(tm, s0[r]);
#pragma unroll
        for (int r = 0; r < 16; ++r) tm = fmaxf(tm, s1[r]);
        tm = fmaxf(tm, __shfl_xor(tm, 32));
        if (__any(tm > m + 8.0f)) {
            float nm = fmaxf(m, tm);
            float alpha = exp2f((m - nm) * cexp);
            m = nm;
            lsum *= alpha;
#pragma unroll
            for (int r = 0; r < 16; ++r) { accO0[r] *= alpha; accO1[r] *= alpha; }
        }
        const float mc = m * cexp;
        f32x16 pv0, pv1;
        float psum = 0.0f;
#pragma unroll
        for (int r = 0; r < 16; ++r) { pv0[r] = exp2f(fmaf(s0[r], cexp, -mc)); psum += pv0[r]; }
#pragma unroll
        for (int r = 0; r < 16; ++r) { pv1[r] = exp2f(fmaf(s1[r], cexp, -mc)); psum += pv1[r]; }
        psum += __shfl_xor(psum, 32);
        lsum += psum;
        bf16x8 vt[8];
#pragma unroll
        for (int db = 0; db < 2; ++db)
#pragma unroll
            for (int ks = 0; ks < 4; ++ks)
                vt[db * 4 + ks] = *(const bf16x8*)((const char*)sV + (32 * db + li) * 128 +
                                                   ((32 * ks + 16 * hi) ^ ((li & 7) << 4)));
#define PV_STEP(ks, PV)                                                              \
        {                                                                            \
            const int rb = 8 * ((ks) & 1);                                           \
            unsigned x1 = f2bf_pack(PV[rb + 0], PV[rb + 1]);                         \
            unsigned x2 = f2bf_pack(PV[rb + 2], PV[rb + 3]);                         \
            unsigned y1 = f2bf_pack(PV[rb + 4], PV[rb + 5]);                         \
            unsigned y2 = f2bf_pack(PV[rb + 6], PV[rb + 7]);                         \
            auto r1 = __builtin_amdgcn_permlane32_swap(x1, y1, false, false);        \
            auto r2 = __builtin_amdgcn_permlane32_swap(x2, y2, false, false);        \
            uint4v pw = { (unsigned)r1[0], (unsigned)r2[0],                          \
                          (unsigned)r1[1], (unsigned)r2[1] };                        \
            bf16x8 pf = __builtin_bit_cast(bf16x8, pw);                              \
            accO0 = __builtin_amdgcn_mfma_f32_32x32x16_bf16(vt[(ks)],     pf, accO0, 0, 0, 0); \
            accO1 = __builtin_amdgcn_mfma_f32_32x32x16_bf16(vt[4 + (ks)], pf, accO1, 0, 0, 0); \
        }
        PV_STEP(0, pv0)
        PV_STEP(1, pv0)
        PV_STEP(2, pv1)
        PV_STEP(3, pv1)
#undef PV_STEP
        __syncthreads();
    }
    const float invl = 1.0f / lsum;
    float* op = O + ((size_t)(b * T_SEQ + qrow) * U_DIM + hd * D_HEAD);
#pragma unroll
    for (int rq = 0; rq < 4; ++rq) {
        f32x4 o0 = { accO0[4 * rq + 0] * invl, accO0[4 * rq + 1] * invl,
                     accO0[4 * rq + 2] * invl, accO0[4 * rq + 3] * invl };
        *(f32x4*)(op + 8 * rq + 4 * hi) = o0;
        f32x4 o1 = { accO1[4 * rq + 0] * invl, accO1[4 * rq + 1] * invl,
                     accO1[4 * rq + 2] * invl, accO1[4 * rq + 3] * invl };
        *(f32x4*)(op + 8 * rq + 4 * hi + 32) = o1;
    }
}

extern "C" void kernel_launch(void* const* d_in, const int* in_sizes, int n_in,
                              void* d_out, int out_size, void* d_ws, size_t ws_size,
                              hipStream_t stream) {
    const float* Q = (const float*)d_in[0];
    const float* K = (const float*)d_in[1];
    const float* V = (const float*)d_in[2];
    float* O = (float*)d_out;
    if (ws_size >= 33554432ull) {
        u16* Kb = (u16*)d_ws;
        u16* Vt = (u16*)((char*)d_ws + 16777216);
        conv_k<<<4096, 256, 0, stream>>>(K, Kb);
        transp_v<<<2048, 256, 0, stream>>>(V, Vt);
        mha_fwd5<<<1024, 256, 0, stream>>>(Q, Kb, Vt, O);
    } else {
        mha_fwd_v1<<<1024, 256, 0, stream>>>(Q, K, V, O);
    }
}

// Round 7
// 106.235 us; speedup vs baseline: 4.0015x; 4.0015x over previous
//
#include <hip/hip_runtime.h>

#define T_SEQ 2048
#define U_DIM 1024
#define H_HEADS 16
#define D_HEAD 64
#define B_BATCH 4
#define KVBLK 64
#define QBLK 256
#define NITER (T_SEQ / KVBLK)

typedef float f32x16 __attribute__((ext_vector_type(16)));
typedef float f32x4  __attribute__((ext_vector_type(4)));
typedef __bf16 bf16x8 __attribute__((ext_vector_type(8)));
typedef unsigned int uint4v __attribute__((ext_vector_type(4)));
typedef unsigned int uint2v __attribute__((ext_vector_type(2)));
typedef unsigned short u16;

// v4-proven exp2 path: builtin (compiler handles the trans-op hazard) or libm.
// Do NOT use inline-asm v_exp_f32 -- R6 showed the hazard nop is not inserted.
#if __has_builtin(__builtin_amdgcn_exp2f)
#define EXP2(x) __builtin_amdgcn_exp2f(x)
#else
#define EXP2(x) exp2f(x)
#endif

__device__ __forceinline__ unsigned f2bf_pack(float lo, float hi) {
    __bf16 a = (__bf16)lo, b = (__bf16)hi;
    unsigned short ua = __builtin_bit_cast(unsigned short, a);
    unsigned short ub = __builtin_bit_cast(unsigned short, b);
    return (unsigned)ua | ((unsigned)ub << 16);
}

__device__ __forceinline__ void gl2lds16(const void* g, void* l) {
    __builtin_amdgcn_global_load_lds(
        (const __attribute__((address_space(1))) void*)g,
        (__attribute__((address_space(3))) void*)l, 16, 0, 0);
}

// ---------------- pre-pass A: K fp32 [b,t,h*64+d] -> bf16 [b,h,t,d] ----------------
__global__ __launch_bounds__(256) void conv_k(const float* __restrict__ K, u16* __restrict__ Kb) {
    unsigned idx = blockIdx.x * 256u + threadIdx.x;   // 2^20 threads
    unsigned d8 = idx & 7, t = (idx >> 3) & 2047, h = (idx >> 14) & 15, b = idx >> 18;
    const float* src = K + (((size_t)(b * 2048 + t)) * 1024 + h * 64 + d8 * 8);
    f32x4 a = *(const f32x4*)src;
    f32x4 c = *(const f32x4*)(src + 4);
    uint4v u = { f2bf_pack(a.x, a.y), f2bf_pack(a.z, a.w),
                 f2bf_pack(c.x, c.y), f2bf_pack(c.z, c.w) };
    *(uint4v*)(Kb + (((size_t)(b * 16 + h) * 2048 + t) * 64 + d8 * 8)) = u;
}

// ---------------- pre-pass B: V fp32 [b,t,h*64+d] -> bf16 transposed [b,h,d,t] ----------------
__global__ __launch_bounds__(256) void transp_v(const float* __restrict__ V, u16* __restrict__ Vt) {
    __shared__ __align__(16) u16 tile[64][72];
    const int tid = threadIdx.x;
    const int bid = blockIdx.x;                  // 2048 = 4b * 16h * 32 t-tiles
    const int tt = bid & 31, h = (bid >> 5) & 15, b = bid >> 9;
    const int t0 = tt * 64;
    {
        const int r = tid >> 2, q = tid & 3;
        const float* src = V + (((size_t)(b * 2048 + t0 + r)) * 1024 + h * 64 + q * 16);
        f32x4 v0 = *(const f32x4*)(src);
        f32x4 v1 = *(const f32x4*)(src + 4);
        f32x4 v2 = *(const f32x4*)(src + 8);
        f32x4 v3 = *(const f32x4*)(src + 12);
#pragma unroll
        for (int j = 0; j < 4; ++j) {
            tile[q * 16 + 0  + j][r] = __builtin_bit_cast(u16, (__bf16)v0[j]);
            tile[q * 16 + 4  + j][r] = __builtin_bit_cast(u16, (__bf16)v1[j]);
            tile[q * 16 + 8  + j][r] = __builtin_bit_cast(u16, (__bf16)v2[j]);
            tile[q * 16 + 12 + j][r] = __builtin_bit_cast(u16, (__bf16)v3[j]);
        }
    }
    __syncthreads();
    {
        const int d = tid >> 2, q = tid & 3;
        u16* dst = Vt + (((size_t)(b * 16 + h) * 64 + d) * 2048 + t0 + q * 16);
        *(uint4v*)(dst)     = *(const uint4v*)&tile[d][q * 16];
        *(uint4v*)(dst + 8) = *(const uint4v*)&tile[d][q * 16 + 8];
    }
}

// ------- main kernel v7: 2 q-blocks per wave (64q x 64k) -> LDS reads per MFMA halved -------
__global__ __launch_bounds__(256, 2) void mha_fwd7(
    const float* __restrict__ Q, const u16* __restrict__ Kb,
    const u16* __restrict__ Vt, float* __restrict__ O)
{
    const int tid  = threadIdx.x;
    const int wave = tid >> 6;
    const int lane = tid & 63;
    const int li   = lane & 31;
    const int hi   = lane >> 5;
    const int sw   = (li & 7) << 4;    // read-side XOR swizzle

    // XCD colocation: bid%8 == bh%8 -> all 8 q-tiles of one (b,h) share an XCD's L2
    const int bid = blockIdx.x;        // 512
    const int bh  = bid & 63;
    const int qt  = bid >> 6;          // 0..7
    const int b   = bh >> 4;

    __shared__ __align__(16) u16 sK[2][4096];   // [buf][key(64) x d(64)] swizzled
    __shared__ __align__(16) u16 sVt[2][4096];  // [buf][d(64) x key(64)] swizzled

    const int c0 = wave * 2;
    const int r0 = lane >> 3;
    const int innerK = ((lane & 7) * 16) ^ (r0 << 4);
    const char* kbg = (const char*)Kb + (size_t)bh * 262144;
    const char* vbg = (const char*)Vt + (size_t)bh * 262144;
    const char* kp0 = kbg + c0 * 1024 + r0 * 128 + innerK;
    const char* kp1 = kbg + (c0 + 1) * 1024 + r0 * 128 + innerK;
    const char* vp0 = vbg + (size_t)(c0 * 8 + r0) * 4096 + innerK;
    const char* vp1 = vbg + (size_t)((c0 + 1) * 8 + r0) * 4096 + innerK;

#define STAGE(BUF) do {                                                   \
        char* kd = (char*)&sK[(BUF)][0] + c0 * 1024;                      \
        gl2lds16(kp0, kd); gl2lds16(kp1, kd + 1024);                      \
        char* vd = (char*)&sVt[(BUF)][0] + c0 * 1024;                     \
        gl2lds16(vp0, vd); gl2lds16(vp1, vd + 1024);                      \
        kp0 += 8192; kp1 += 8192; vp0 += 128; vp1 += 128; } while (0)

    STAGE(0);   // prologue prefetch of tile 0

    // ---- Q fragments for both q-blocks, (1/8)*log2(e) folded in ----
    const float cexp = 0.18033688011112042f;
    const int qrowA = qt * QBLK + wave * 32 + li;    // rows 0..127 of the 256-tile
    const int qrowB = qrowA + 128;                   // rows 128..255
    bf16x8 qfA[4], qfB[4];
    {
        const float* qpA = Q + ((size_t)(b * T_SEQ + qrowA) * U_DIM + (bh & 15) * D_HEAD);
        const float* qpB = Q + ((size_t)(b * T_SEQ + qrowB) * U_DIM + (bh & 15) * D_HEAD);
#pragma unroll
        for (int ds = 0; ds < 4; ++ds) {
            f32x4 a = *(const f32x4*)(qpA + 16 * ds + 8 * hi);
            f32x4 c = *(const f32x4*)(qpA + 16 * ds + 8 * hi + 4);
            uint4v u = { f2bf_pack(a.x * cexp, a.y * cexp), f2bf_pack(a.z * cexp, a.w * cexp),
                         f2bf_pack(c.x * cexp, c.y * cexp), f2bf_pack(c.z * cexp, c.w * cexp) };
            qfA[ds] = __builtin_bit_cast(bf16x8, u);
            f32x4 a2 = *(const f32x4*)(qpB + 16 * ds + 8 * hi);
            f32x4 c2 = *(const f32x4*)(qpB + 16 * ds + 8 * hi + 4);
            uint4v u2 = { f2bf_pack(a2.x * cexp, a2.y * cexp), f2bf_pack(a2.z * cexp, a2.w * cexp),
                          f2bf_pack(c2.x * cexp, c2.y * cexp), f2bf_pack(c2.z * cexp, c2.w * cexp) };
            qfB[ds] = __builtin_bit_cast(bf16x8, u2);
        }
    }

    float lA = 0.0f, lB = 0.0f;
    f32x16 accA0 = {}, accA1 = {}, accB0 = {}, accB1 = {};
    int buf = 0;

    // pack 8 probs of S (rows RB..RB+7) for one q-block and run its 2 PV MFMAs;
    // vta/vtb are shared between the A and B q-blocks (one LDS read, two uses).
#define PVGROUP(KS, RB)                                                          \
    {                                                                            \
        bf16x8 vta = *(const bf16x8*)(vb_l + li * 128 + ((32 * (KS) + 16 * hi) ^ sw));        \
        bf16x8 vtb = *(const bf16x8*)(vb_l + (32 + li) * 128 + ((32 * (KS) + 16 * hi) ^ sw)); \
        unsigned ax1 = f2bf_pack(sA[(RB) + 0], sA[(RB) + 1]);                    \
        unsigned ax2 = f2bf_pack(sA[(RB) + 2], sA[(RB) + 3]);                    \
        unsigned ay1 = f2bf_pack(sA[(RB) + 4], sA[(RB) + 5]);                    \
        unsigned ay2 = f2bf_pack(sA[(RB) + 6], sA[(RB) + 7]);                    \
        auto ar1 = __builtin_amdgcn_permlane32_swap(ax1, ay1, false, false);     \
        auto ar2 = __builtin_amdgcn_permlane32_swap(ax2, ay2, false, false);     \
        uint4v apw = { (unsigned)ar1[0], (unsigned)ar2[0],                       \
                       (unsigned)ar1[1], (unsigned)ar2[1] };                     \
        bf16x8 pfA = __builtin_bit_cast(bf16x8, apw);                            \
        accA0 = __builtin_amdgcn_mfma_f32_32x32x16_bf16(vta, pfA, accA0, 0, 0, 0); \
        accA1 = __builtin_amdgcn_mfma_f32_32x32x16_bf16(vtb, pfA, accA1, 0, 0, 0); \
        unsigned bx1 = f2bf_pack(sB[(RB) + 0], sB[(RB) + 1]);                    \
        unsigned bx2 = f2bf_pack(sB[(RB) + 2], sB[(RB) + 3]);                    \
        unsigned by1 = f2bf_pack(sB[(RB) + 4], sB[(RB) + 5]);                    \
        unsigned by2 = f2bf_pack(sB[(RB) + 6], sB[(RB) + 7]);                    \
        auto br1 = __builtin_amdgcn_permlane32_swap(bx1, by1, false, false);     \
        auto br2 = __builtin_amdgcn_permlane32_swap(bx2, by2, false, false);     \
        uint4v bpw = { (unsigned)br1[0], (unsigned)br2[0],                       \
                       (unsigned)br1[1], (unsigned)br2[1] };                     \
        bf16x8 pfB = __builtin_bit_cast(bf16x8, bpw);                            \
        accB0 = __builtin_amdgcn_mfma_f32_32x32x16_bf16(vta, pfB, accB0, 0, 0, 0); \
        accB1 = __builtin_amdgcn_mfma_f32_32x32x16_bf16(vtb, pfB, accB1, 0, 0, 0); \
    }

    // one key-half (32 keys): 4 K-reads feed 8 QK MFMAs (A+B), exp both S tiles,
    // denominator trees, then 2 PVGROUPs (4 V-reads feed 8 PV MFMAs).
#define HALF(ROWOFF, KS0)                                                        \
    {                                                                            \
        f32x16 sA = {}, sB = {};                                                 \
        _Pragma("unroll")                                                        \
        for (int ds = 0; ds < 4; ++ds) {                                         \
            bf16x8 kf = *(const bf16x8*)(kb_l + ((ROWOFF) + li) * 128 +          \
                                         ((32 * ds + 16 * hi) ^ sw));            \
            sA = __builtin_amdgcn_mfma_f32_32x32x16_bf16(kf, qfA[ds], sA, 0, 0, 0); \
            sB = __builtin_amdgcn_mfma_f32_32x32x16_bf16(kf, qfB[ds], sB, 0, 0, 0); \
        }                                                                        \
        _Pragma("unroll") for (int r = 0; r < 16; ++r) sA[r] = EXP2(sA[r]);      \
        _Pragma("unroll") for (int r = 0; r < 16; ++r) sB[r] = EXP2(sB[r]);      \
        {                                                                        \
            float a0 = (sA[0] + sA[1]) + (sA[2] + sA[3]);                        \
            float a1 = (sA[4] + sA[5]) + (sA[6] + sA[7]);                        \
            float a2 = (sA[8] + sA[9]) + (sA[10] + sA[11]);                      \
            float a3 = (sA[12] + sA[13]) + (sA[14] + sA[15]);                    \
            lA += (a0 + a1) + (a2 + a3);                                         \
            float b0 = (sB[0] + sB[1]) + (sB[2] + sB[3]);                        \
            float b1 = (sB[4] + sB[5]) + (sB[6] + sB[7]);                        \
            float b2 = (sB[8] + sB[9]) + (sB[10] + sB[11]);                      \
            float b3 = (sB[12] + sB[13]) + (sB[14] + sB[15]);                    \
            lB += (b0 + b1) + (b2 + b3);                                         \
        }                                                                        \
        PVGROUP((KS0), 0)                                                        \
        PVGROUP((KS0) + 1, 8)                                                    \
    }

#pragma unroll 2
    for (int it = 0; it < NITER; ++it) {
        asm volatile("s_waitcnt vmcnt(0)" ::: "memory");
        __builtin_amdgcn_s_barrier();
        asm volatile("" ::: "memory");
        if (it + 1 < NITER) { STAGE(buf ^ 1); }   // prefetch next tile

        const char* kb_l = (const char*)&sK[buf][0];
        const char* vb_l = (const char*)&sVt[buf][0];

        __builtin_amdgcn_s_setprio(1);
        HALF(0, 0)      // keys 0..31  (K rows li),    V ks 0,1
        HALF(32, 2)     // keys 32..63 (K rows 32+li), V ks 2,3
        __builtin_amdgcn_s_setprio(0);

        buf ^= 1;
    }
#undef STAGE
#undef PVGROUP
#undef HALF

    // ---- epilogue: normalize and store both q-blocks ----
    float ltA = lA + __shfl_xor(lA, 32);
    float ltB = lB + __shfl_xor(lB, 32);
    const float invA = 1.0f / ltA;
    const float invB = 1.0f / ltB;
    float* opA = O + ((size_t)(b * T_SEQ + qrowA) * U_DIM + (bh & 15) * D_HEAD);
    float* opB = O + ((size_t)(b * T_SEQ + qrowB) * U_DIM + (bh & 15) * D_HEAD);
#pragma unroll
    for (int rq = 0; rq < 4; ++rq) {
        f32x4 oa0 = { accA0[4 * rq + 0] * invA, accA0[4 * rq + 1] * invA,
                      accA0[4 * rq + 2] * invA, accA0[4 * rq + 3] * invA };
        *(f32x4*)(opA + 8 * rq + 4 * hi) = oa0;
        f32x4 oa1 = { accA1[4 * rq + 0] * invA, accA1[4 * rq + 1] * invA,
                      accA1[4 * rq + 2] * invA, accA1[4 * rq + 3] * invA };
        *(f32x4*)(opA + 8 * rq + 4 * hi + 32) = oa1;
        f32x4 ob0 = { accB0[4 * rq + 0] * invB, accB0[4 * rq + 1] * invB,
                      accB0[4 * rq + 2] * invB, accB0[4 * rq + 3] * invB };
        *(f32x4*)(opB + 8 * rq + 4 * hi) = ob0;
        f32x4 ob1 = { accB1[4 * rq + 0] * invB, accB1[4 * rq + 1] * invB,
                      accB1[4 * rq + 2] * invB, accB1[4 * rq + 3] * invB };
        *(f32x4*)(opB + 8 * rq + 4 * hi + 32) = ob1;
    }
}

// ---------------- fallback (round-1 kernel, known good) for small ws ----------------
__global__ __launch_bounds__(256, 2) void mha_fwd_v1(
    const float* __restrict__ Q, const float* __restrict__ K,
    const float* __restrict__ V, float* __restrict__ O)
{
    const int tid  = threadIdx.x;
    const int wave = tid >> 6;
    const int lane = tid & 63;
    const int li   = lane & 31;
    const int hi   = lane >> 5;
    const int bid = blockIdx.x;
    const int qt  = bid & 15;
    const int bh  = bid >> 4;
    const int b   = bh >> 4;
    const int hd  = bh & 15;
    __shared__ __align__(16) u16 sK[KVBLK * D_HEAD];
    __shared__ __align__(16) u16 sV[KVBLK * D_HEAD];
    const int qrow = qt * 128 + wave * 32 + li;
    const float* qp = Q + ((size_t)(b * T_SEQ + qrow) * U_DIM + hd * D_HEAD);
    bf16x8 qfrag[4];
#pragma unroll
    for (int ds = 0; ds < 4; ++ds) {
        f32x4 a = *(const f32x4*)(qp + 16 * ds + 8 * hi);
        f32x4 c = *(const f32x4*)(qp + 16 * ds + 8 * hi + 4);
        uint4v u = { f2bf_pack(a.x, a.y), f2bf_pack(a.z, a.w),
                     f2bf_pack(c.x, c.y), f2bf_pack(c.z, c.w) };
        qfrag[ds] = __builtin_bit_cast(bf16x8, u);
    }
    const int d4 = tid & 15;
    const int kq = tid >> 4;
    const float* kbase = K + ((size_t)(b * T_SEQ) * U_DIM + hd * D_HEAD);
    const float* vbase = V + ((size_t)(b * T_SEQ) * U_DIM + hd * D_HEAD);
    const float cexp = 0.18033688011112042f;
    float m = -INFINITY, lsum = 0.0f;
    f32x16 accO0 = {}, accO1 = {};
    for (int it = 0; it < NITER; ++it) {
        const int kv0 = it * KVBLK;
        {
            const float* kr = kbase + (size_t)(kv0 + 4 * kq) * U_DIM + 4 * d4;
            const float* vr = vbase + (size_t)(kv0 + 4 * kq) * U_DIM + 4 * d4;
            f32x4 kv[4], vv[4];
#pragma unroll
            for (int i = 0; i < 4; ++i) {
                kv[i] = *(const f32x4*)(kr + i * U_DIM);
                vv[i] = *(const f32x4*)(vr + i * U_DIM);
            }
#pragma unroll
            for (int i = 0; i < 4; ++i) {
                int row = 4 * kq + i;
                char* dst = (char*)sK + row * 128 + ((8 * d4) ^ ((row & 7) << 4));
                uint2v w = { f2bf_pack(kv[i].x, kv[i].y), f2bf_pack(kv[i].z, kv[i].w) };
                *(uint2v*)dst = w;
            }
#pragma unroll
            for (int jj = 0; jj < 4; ++jj) {
                int row = 4 * d4 + jj;
                char* dst = (char*)sV + row * 128 + ((8 * kq) ^ ((row & 7) << 4));
                uint2v w = { f2bf_pack(vv[0][jj], vv[1][jj]),
                             f2bf_pack(vv[2][jj], vv[3][jj]) };
                *(uint2v*)dst = w;
            }
        }
        __syncthreads();
        f32x16 s0 = {}, s1 = {};
#pragma unroll
        for (int ds = 0; ds < 4; ++ds) {
            bf16x8 kf0 = *(const bf16x8*)((const char*)sK + li * 128 +
                                          ((32 * ds + 16 * hi) ^ ((li & 7) << 4)));
            bf16x8 kf1 = *(const bf16x8*)((const char*)sK + (32 + li) * 128 +
                                          ((32 * ds + 16 * hi) ^ ((li & 7) << 4)));
            s0 = __builtin_amdgcn_mfma_f32_32x32x16_bf16(kf0, qfrag[ds], s0, 0, 0, 0);
            s1 = __builtin_amdgcn_mfma_f32_32x32x16_bf16(kf1, qfrag[ds], s1, 0, 0, 0);
        }
        float tm = s0[0];
#pragma unroll
        for (int r = 1; r < 16; ++r) tm = fmaxf(tm, s0[r]);
#pragma unroll
        for (int r = 0; r < 16; ++r) tm = fmaxf(tm, s1[r]);
        tm = fmaxf(tm, __shfl_xor(tm, 32));
        if (__any(tm > m + 8.0f)) {
            float nm = fmaxf(m, tm);
            float alpha = exp2f((m - nm) * cexp);
            m = nm;
            lsum *= alpha;
#pragma unroll
            for (int r = 0; r < 16; ++r) { accO0[r] *= alpha; accO1[r] *= alpha; }
        }
        const float mc = m * cexp;
        f32x16 pv0, pv1;
        float psum = 0.0f;
#pragma unroll
        for (int r = 0; r < 16; ++r) { pv0[r] = exp2f(fmaf(s0[r], cexp, -mc)); psum += pv0[r]; }
#pragma unroll
        for (int r = 0; r < 16; ++r) { pv1[r] = exp2f(fmaf(s1[r], cexp, -mc)); psum += pv1[r]; }
        psum += __shfl_xor(psum, 32);
        lsum += psum;
        bf16x8 vt[8];
#pragma unroll
        for (int db = 0; db < 2; ++db)
#pragma unroll
            for (int ks = 0; ks < 4; ++ks)
                vt[db * 4 + ks] = *(const bf16x8*)((const char*)sV + (32 * db + li) * 128 +
                                                   ((32 * ks + 16 * hi) ^ ((li & 7) << 4)));
#define PV_STEP(ks, PV)                                                              \
        {                                                                            \
            const int rb = 8 * ((ks) & 1);                                           \
            unsigned x1 = f2bf_pack(PV[rb + 0], PV[rb + 1]);                         \
            unsigned x2 = f2bf_pack(PV[rb + 2], PV[rb + 3]);                         \
            unsigned y1 = f2bf_pack(PV[rb + 4], PV[rb + 5]);                         \
            unsigned y2 = f2bf_pack(PV[rb + 6], PV[rb + 7]);                         \
            auto r1 = __builtin_amdgcn_permlane32_swap(x1, y1, false, false);        \
            auto r2 = __builtin_amdgcn_permlane32_swap(x2, y2, false, false);        \
            uint4v pw = { (unsigned)r1[0], (unsigned)r2[0],                          \
                          (unsigned)r1[1], (unsigned)r2[1] };                        \
            bf16x8 pf = __builtin_bit_cast(bf16x8, pw);                              \
            accO0 = __builtin_amdgcn_mfma_f32_32x32x16_bf16(vt[(ks)],     pf, accO0, 0, 0, 0); \
            accO1 = __builtin_amdgcn_mfma_f32_32x32x16_bf16(vt[4 + (ks)], pf, accO1, 0, 0, 0); \
        }
        PV_STEP(0, pv0)
        PV_STEP(1, pv0)
        PV_STEP(2, pv1)
        PV_STEP(3, pv1)
#undef PV_STEP
        __syncthreads();
    }
    const float invl = 1.0f / lsum;
    float* op = O + ((size_t)(b * T_SEQ + qrow) * U_DIM + hd * D_HEAD);
#pragma unroll
    for (int rq = 0; rq < 4; ++rq) {
        f32x4 o0 = { accO0[4 * rq + 0] * invl, accO0[4 * rq + 1] * invl,
                     accO0[4 * rq + 2] * invl, accO0[4 * rq + 3] * invl };
        *(f32x4*)(op + 8 * rq + 4 * hi) = o0;
        f32x4 o1 = { accO1[4 * rq + 0] * invl, accO1[4 * rq + 1] * invl,
                     accO1[4 * rq + 2] * invl, accO1[4 * rq + 3] * invl };
        *(f32x4*)(op + 8 * rq + 4 * hi + 32) = o1;
    }
}

extern "C" void kernel_launch(void* const* d_in, const int* in_sizes, int n_in,
                              void* d_out, int out_size, void* d_ws, size_t ws_size,
                              hipStream_t stream) {
    const float* Q = (const float*)d_in[0];
    const float* K = (const float*)d_in[1];
    const float* V = (const float*)d_in[2];
    float* O = (float*)d_out;
    if (ws_size >= 33554432ull) {
        u16* Kb = (u16*)d_ws;
        u16* Vt = (u16*)((char*)d_ws + 16777216);
        conv_k<<<4096, 256, 0, stream>>>(K, Kb);
        transp_v<<<2048, 256, 0, stream>>>(V, Vt);
        mha_fwd7<<<512, 256, 0, stream>>>(Q, Kb, Vt, O);   // 64 bh * 8 qtiles of 256
    } else {
        mha_fwd_v1<<<1024, 256, 0, stream>>>(Q, K, V, O);
    }
}